// Round 18
// baseline (68.725 us; speedup 1.0000x reference)
//
#include <hip/hip_runtime.h>
#include <stdint.h>

#define HW_  9216
#define S_   2304
#define NBH  16
#define NSPLIT 2
#define JPS  18         // KV tiles per split (36/2)
#define NPART ((size_t)NBH * S_ * 64)
// 0.5 (softmax scale = 1/sqrt(head_size=4)) * log2(e), folded into Wq/bq
#define SCALE_LOG2E 0.72134752044448169136f

using f32x4 = __attribute__((ext_vector_type(4))) float;
using u32x4 = __attribute__((ext_vector_type(4))) uint32_t;
using u32x2 = __attribute__((ext_vector_type(2))) uint32_t;
using s16x8 = __attribute__((ext_vector_type(8))) short;   // 8 bf16 in 4 VGPRs

typedef const __attribute__((address_space(1))) void gbl_void;
typedef __attribute__((address_space(3))) void lds_void;

__device__ __forceinline__ uint32_t pkbf(float lo, float hi) {
    uint32_t r;
    asm("v_cvt_pk_bf16_f32 %0, %1, %2" : "=v"(r) : "v"(lo), "v"(hi));
    return r;
}
__device__ __forceinline__ float bf2f(uint16_t h) {
    return __builtin_bit_cast(float, (uint32_t)h << 16);
}

// ---------------------------------------------------------------------------
// Kernel 1: FUSED qkv projection, MFMA. grid=1152, block=192 (3 waves),
// 32-pixel tiles (was 64). Waves 0-1 cooperatively transpose the x-tile
// (lane = pixel x channel-quarter; one barrier: write -> sync -> read, the
// verified pattern); wave 2's W-fragment loads overlap the transpose.
// Wave w computes its whole mode (w=0:Q, 1:K, 2:V) with the R10-verified
// fragment/epilogue formulas (nt/mt tile counts adapted to 32 pixels).
// ---------------------------------------------------------------------------
__global__ __launch_bounds__(192) void qkv_fused(
    const float* __restrict__ x,
    const float* __restrict__ Wq, const float* __restrict__ Wk, const float* __restrict__ Wv,
    const float* __restrict__ bq, const float* __restrict__ bk, const float* __restrict__ bv,
    uint16_t* __restrict__ Qo, uint16_t* __restrict__ Ko, uint16_t* __restrict__ Vo)
{
    const int pix0 = blockIdx.x * 32;
    const int b   = pix0 / HW_;
    const int hw0 = pix0 % HW_;
    const int h   = hw0 / S_;          // uniform (32 | S_)
    const int s0  = hw0 % S_;
    const int bh  = b * 4 + h;

    const int tid  = threadIdx.x;
    const int wave = tid >> 6;          // 0..2 == mode
    const int lane = tid & 63;
    const int g = lane >> 4, lr = lane & 15;

    __shared__ alignas(16) uint16_t xt[32 * 64];   // [pix][c] bf16, swizzled

    // ---- cooperative x-tile stage: waves 0-1; lane owns (pixel, quarter) ----
    if (wave < 2) {
        const int pix = lane & 31;
        const int q4  = wave * 2 + (lane >> 5);    // channel quarter 0..3
        const float* xb = x + (size_t)b * 64 * HW_ + hw0 + pix;
        #pragma unroll
        for (int cbi = 0; cbi < 2; ++cbi) {
            const int cb = q4 * 2 + cbi;
            uint32_t rp[4];
            #pragma unroll
            for (int e = 0; e < 4; ++e)
                rp[e] = pkbf(xb[(size_t)(cb * 8 + 2 * e) * HW_],
                             xb[(size_t)(cb * 8 + 2 * e + 1) * HW_]);
            u32x4 d = { rp[0], rp[1], rp[2], rp[3] };
            *(u32x4*)(xt + pix * 64 + 8 * (cb ^ (pix & 7))) = d;
        }
    }

    const float* W    = (wave == 0) ? Wq : (wave == 1) ? Wk : Wv;
    const float* bias = (wave == 0) ? bq : (wave == 1) ? bk : bv;
    const float ws = (wave == 0) ? SCALE_LOG2E : 1.0f;

    // ---- W fragments (scale folded for Q); overlaps the transpose ----
    s16x8 wf[4][2];
    #pragma unroll
    for (int t4 = 0; t4 < 4; ++t4)
        #pragma unroll
        for (int ks = 0; ks < 2; ++ks) {
            const float* wp = W + (t4 * 16 + lr) * 64 + ks * 32 + g * 8;
            f32x4 w0 = *(const f32x4*)wp;
            f32x4 w1 = *(const f32x4*)(wp + 4);
            u32x4 d = { pkbf(w0[0] * ws, w0[1] * ws), pkbf(w0[2] * ws, w0[3] * ws),
                        pkbf(w1[0] * ws, w1[1] * ws), pkbf(w1[2] * ws, w1[3] * ws) };
            wf[t4][ks] = __builtin_bit_cast(s16x8, d);
        }

    __syncthreads();   // transpose writes visible before any fragment read

    // ---- x fragments from LDS (2 pixel tiles) ----
    s16x8 xf[2][2];
    #pragma unroll
    for (int pt = 0; pt < 2; ++pt)
        #pragma unroll
        for (int ks = 0; ks < 2; ++ks) {
            const int pix = pt * 16 + lr;
            xf[pt][ks] = *(const s16x8*)(xt + pix * 64 + 8 * ((ks * 4 + g) ^ (pix & 7)));
        }

    if (wave != 2) {
        f32x4 acc[4][2];
        #pragma unroll
        for (int mt = 0; mt < 4; ++mt) {
            f32x4 bi = *(const f32x4*)(bias + mt * 16 + g * 4);
            bi *= ws;
            #pragma unroll
            for (int nt = 0; nt < 2; ++nt) acc[mt][nt] = bi;
        }
        #pragma unroll
        for (int ks = 0; ks < 2; ++ks)
            #pragma unroll
            for (int mt = 0; mt < 4; ++mt)
                #pragma unroll
                for (int nt = 0; nt < 2; ++nt)
                    acc[mt][nt] = __builtin_amdgcn_mfma_f32_16x16x32_bf16(
                        wf[mt][ks], xf[nt][ks], acc[mt][nt], 0, 0, 0);
        uint16_t* dst = ((wave == 0) ? Qo : Ko) + ((size_t)bh * S_ + s0) * 64;
        #pragma unroll
        for (int mt = 0; mt < 4; ++mt)
            #pragma unroll
            for (int nt = 0; nt < 2; ++nt) {
                uint32_t d0 = pkbf(acc[mt][nt][0], acc[mt][nt][1]);
                uint32_t d1 = pkbf(acc[mt][nt][2], acc[mt][nt][3]);
                const int o = mt * 16 + g * 4;
                *(uint32_t*)(dst + (nt * 16 + lr) * 64 + o)     = d0;
                *(uint32_t*)(dst + (nt * 16 + lr) * 64 + o + 2) = d1;
            }
    } else {
        f32x4 acc[2][4];
        #pragma unroll
        for (int nt = 0; nt < 4; ++nt) {
            const float bv = bias[nt * 16 + lr];
            #pragma unroll
            for (int mt = 0; mt < 2; ++mt) acc[mt][nt] = (f32x4){bv, bv, bv, bv};
        }
        #pragma unroll
        for (int ks = 0; ks < 2; ++ks)
            #pragma unroll
            for (int mt = 0; mt < 2; ++mt)
                #pragma unroll
                for (int nt = 0; nt < 4; ++nt)
                    acc[mt][nt] = __builtin_amdgcn_mfma_f32_16x16x32_bf16(
                        xf[mt][ks], wf[nt][ks], acc[mt][nt], 0, 0, 0);
        uint16_t* dst = Vo + (size_t)bh * 64 * S_;
        #pragma unroll
        for (int mt = 0; mt < 2; ++mt)
            #pragma unroll
            for (int nt = 0; nt < 4; ++nt) {
                uint32_t d0 = pkbf(acc[mt][nt][0], acc[mt][nt][1]);
                uint32_t d1 = pkbf(acc[mt][nt][2], acc[mt][nt][3]);
                const int o = nt * 16 + lr;
                const int sb = s0 + mt * 16 + g * 4;
                *(uint32_t*)(dst + (size_t)o * S_ + sb)     = d0;
                *(uint32_t*)(dst + (size_t)o * S_ + sb + 2) = d1;
            }
    }
}

// ---------------------------------------------------------------------------
// Kernel 2: flash attention, no-max softmax, split-KV x2. grid=576, block=256.
// Kernel body BYTE-EXACT the R7/R10/R14/R17-verified anchor; only the grid
// decomposition constants change (NSPLIT knob verified at 3 and 4).
// Serialized staging: stage -> vmcnt(0) -> barrier -> compute -> barrier.
// Stores UNNORMALIZED bf16 partial-O + f32 partial-l; out_proj merges.
// DO NOT restructure staging/P-lifetime (R4/5/8/9/13/15/16 all failed there).
// ---------------------------------------------------------------------------
__global__ __launch_bounds__(256, 3) void attn(
    const uint16_t* __restrict__ Qg, const uint16_t* __restrict__ Kg,
    const uint16_t* __restrict__ Vg, uint16_t* __restrict__ Op,
    float* __restrict__ Lp)
{
    const int blk = blockIdx.x;          // 576 = 8 xcd * 2 bh * (2 sp * 18 qb)
    const int xcd = blk & 7;
    const int i   = blk >> 3;            // 0..71
    const int bh  = xcd * 2 + (i & 1);
    const int i2  = i >> 1;              // 0..35
    const int sp  = i2 & 1;
    const int qb  = i2 >> 1;             // 0..17
    const int j0  = sp * JPS;
    const int b   = bh >> 2;
    const int h   = bh & 3;

    const int tid  = threadIdx.x;
    const int wave = tid >> 6;
    const int lane = tid & 63;
    const int g    = lane >> 4;
    const int lr   = lane & 15;
    const int q0   = qb * 128 + wave * 32;

    __shared__ alignas(16) uint16_t Kl[4096];      // [key][c] swizzled
    __shared__ alignas(16) uint16_t Vl[4096];      // [c][s]   swizzled
    __shared__ alignas(16) uint16_t Pw[4][2304];   // per-wave P (stride 72) / out-bounce (stride 36)
    uint16_t* P = Pw[wave];

    const uint16_t* Qb = Qg + (size_t)bh * S_ * 64;
    const uint16_t* Kb = Kg + (size_t)bh * S_ * 64;
    const uint16_t* Vb = Vg + (size_t)bh * 64 * S_;

    s16x8 qf[2][2];
    #pragma unroll
    for (int qt = 0; qt < 2; ++qt)
        #pragma unroll
        for (int ks = 0; ks < 2; ++ks)
            qf[qt][ks] = *(const s16x8*)(Qb + (size_t)(q0 + qt * 16 + lr) * 64 + ks * 32 + g * 8);

    f32x4 oacc[2][4];
    float l_r[2][4];
    #pragma unroll
    for (int qt = 0; qt < 2; ++qt) {
        #pragma unroll
        for (int ct = 0; ct < 4; ++ct) oacc[qt][ct] = (f32x4){0.f, 0.f, 0.f, 0.f};
        #pragma unroll
        for (int r = 0; r < 4; ++r) l_r[qt][r] = 0.f;
    }

    for (int jj = 0; jj < JPS; ++jj) {
        const int j = j0 + jj;
        // ---- stage K/V tile (serialized; each wave stages its quarter) ----
        #pragma unroll
        for (int call = 0; call < 2; ++call) {
            const int chunk = wave * 128 + call * 64 + lane;   // 16B units
            const int row   = chunk >> 3;
            const int cb    = (chunk & 7) ^ (row & 7);         // pre-swizzled source
            __builtin_amdgcn_global_load_lds(
                (gbl_void*)(Kb + ((size_t)(j * 64 + row) * 64 + cb * 8)),
                (lds_void*)(Kl + (wave * 128 + call * 64) * 8), 16, 0, 0);
            __builtin_amdgcn_global_load_lds(
                (gbl_void*)(Vb + ((size_t)row * S_ + j * 64 + cb * 8)),
                (lds_void*)(Vl + (wave * 128 + call * 64) * 8), 16, 0, 0);
        }
        asm volatile("s_waitcnt vmcnt(0)" ::: "memory");
        __syncthreads();

        // ---- S = Q K^T (logits pre-scaled into exp2 domain) ----
        f32x4 sacc[2][4];
        #pragma unroll
        for (int qt = 0; qt < 2; ++qt)
            #pragma unroll
            for (int kt = 0; kt < 4; ++kt) sacc[qt][kt] = (f32x4){0.f, 0.f, 0.f, 0.f};
        #pragma unroll
        for (int ks = 0; ks < 2; ++ks)
            #pragma unroll
            for (int kt = 0; kt < 4; ++kt) {
                const int key = kt * 16 + lr;
                s16x8 kf = *(const s16x8*)(&Kl[key * 64 + 8 * ((ks * 4 + g) ^ (key & 7))]);
                sacc[0][kt] = __builtin_amdgcn_mfma_f32_16x16x32_bf16(qf[0][ks], kf, sacc[0][kt], 0, 0, 0);
                sacc[1][kt] = __builtin_amdgcn_mfma_f32_16x16x32_bf16(qf[1][ks], kf, sacc[1][kt], 0, 0, 0);
            }

        // ---- P = exp2(S), lane-partial l, P -> wave-private LDS ----
        #pragma unroll
        for (int qt = 0; qt < 2; ++qt)
            #pragma unroll
            for (int kt = 0; kt < 4; ++kt)
                #pragma unroll
                for (int r = 0; r < 4; ++r) {
                    const float pv = __builtin_amdgcn_exp2f(sacc[qt][kt][r]);
                    l_r[qt][r] += pv;
                    P[(qt * 16 + 4 * g + r) * 72 + kt * 16 + lr] = (uint16_t)pkbf(pv, pv);
                }

        // ---- PV ----
        #pragma unroll
        for (int ks = 0; ks < 2; ++ks) {
            s16x8 pf0 = *(const s16x8*)(P + (0 * 16 + lr) * 72 + ks * 32 + g * 8);
            s16x8 pf1 = *(const s16x8*)(P + (1 * 16 + lr) * 72 + ks * 32 + g * 8);
            #pragma unroll
            for (int ct = 0; ct < 4; ++ct) {
                const int c = ct * 16 + lr;
                s16x8 vf = *(const s16x8*)(&Vl[c * 64 + 8 * ((ks * 4 + g) ^ (c & 7))]);
                oacc[0][ct] = __builtin_amdgcn_mfma_f32_16x16x32_bf16(pf0, vf, oacc[0][ct], 0, 0, 0);
                oacc[1][ct] = __builtin_amdgcn_mfma_f32_16x16x32_bf16(pf1, vf, oacc[1][ct], 0, 0, 0);
            }
        }

        __syncthreads();   // all waves done reading Kl/Vl before next stage
    }

    // ---- reduce l over the 16-lane group ----
    #pragma unroll
    for (int mask = 1; mask < 16; mask <<= 1) {
        #pragma unroll
        for (int qt = 0; qt < 2; ++qt)
            #pragma unroll
            for (int r = 0; r < 4; ++r)
                l_r[qt][r] += __shfl_xor(l_r[qt][r], mask, 64);
    }

    // ---- bounce UNNORMALIZED O as [c][t] (stride 36 u16) into own P region ----
    #pragma unroll
    for (int qt = 0; qt < 2; ++qt)
        #pragma unroll
        for (int ct = 0; ct < 4; ++ct) {
            uint32_t d0 = pkbf(oacc[qt][ct][0], oacc[qt][ct][1]);
            uint32_t d1 = pkbf(oacc[qt][ct][2], oacc[qt][ct][3]);
            const int base = (ct * 16 + lr) * 36 + qt * 16 + 4 * g;
            *(uint32_t*)(P + base)     = d0;
            *(uint32_t*)(P + base + 2) = d1;
        }
    __syncthreads();   // order cross-lane bounce write -> read

    // ---- scrambled-layout store: lane owns channel c, 32 consecutive t ----
    const int c = lane;
    u32x2 wv[8];
    #pragma unroll
    for (int e = 0; e < 8; ++e)
        wv[e] = *(const u32x2*)(P + c * 36 + e * 4);
    uint16_t* dst = Op + (size_t)sp * NPART
                  + ((size_t)(b * 64 + h * 16 + (c >> 2)) * HW_ + (c & 3) * S_ + q0);
    #pragma unroll
    for (int s4 = 0; s4 < 4; ++s4) {
        u32x4 d = { wv[2 * s4][0], wv[2 * s4][1], wv[2 * s4 + 1][0], wv[2 * s4 + 1][1] };
        *(u32x4*)(dst + s4 * 8) = d;
    }

    if (lr == 0) {
        #pragma unroll
        for (int qt = 0; qt < 2; ++qt)
            #pragma unroll
            for (int r = 0; r < 4; ++r)
                Lp[((size_t)sp * NBH + bh) * S_ + q0 + qt * 16 + 4 * g + r] = l_r[qt][r];
    }
}

// ---------------------------------------------------------------------------
// Kernel 3: merge splits + output projection + residual, MFMA.
// grid=576, block=128 (2 waves). (byte-exact R14/R17-verified cooperative
// kernel; NSPLIT define now 2 -> merge loop 2-deep)
// ---------------------------------------------------------------------------
__global__ __launch_bounds__(128) void out_proj(
    const uint16_t* __restrict__ Op, const float* __restrict__ Lp,
    const float* __restrict__ x,
    const float* __restrict__ Wo, const float* __restrict__ bo,
    float* __restrict__ out)
{
    const int pix0 = blockIdx.x * 64;
    const int b   = pix0 / HW_;
    const int hw0 = pix0 % HW_;
    const int tid  = threadIdx.x;
    const int wave = tid >> 6;           // 0..1
    const int lane = tid & 63;
    const int g = lane >> 4, lr = lane & 15;
    const int o0 = wave * 32;
    const int t = (hw0 % S_) + lane;     // token of own pixel

    __shared__ alignas(16) uint16_t at[64 * 64];   // [pix][c'] bf16, swizzled

    float inv[4];
    #pragma unroll
    for (int hh = 0; hh < 4; ++hh) {
        float sl = 0.f;
        #pragma unroll
        for (int sp2 = 0; sp2 < NSPLIT; ++sp2)
            sl += Lp[((size_t)sp2 * NBH + b * 4 + hh) * S_ + t];
        inv[hh] = 1.0f / sl;
    }

    // ---- cooperative merge: wave w handles cb in [4w, 4w+4) (8 ch each) ----
    {
        const size_t base = (size_t)b * 64 * HW_ + hw0 + lane;
        #pragma unroll
        for (int cbi = 0; cbi < 4; ++cbi) {
            const int cb = wave * 4 + cbi;
            uint32_t rp[4];
            #pragma unroll
            for (int e = 0; e < 4; ++e) {
                const int cc = cb * 4 + e;          // channel pair (2cc, 2cc+1)
                float a0 = 0.f, a1 = 0.f;
                #pragma unroll
                for (int sp2 = 0; sp2 < NSPLIT; ++sp2) {
                    const size_t o2 = (size_t)sp2 * NPART + base;
                    a0 += bf2f(Op[o2 + (size_t)(2 * cc) * HW_]);
                    a1 += bf2f(Op[o2 + (size_t)(2 * cc + 1) * HW_]);
                }
                rp[e] = pkbf(a0 * inv[(2 * cc) >> 4], a1 * inv[(2 * cc + 1) >> 4]);
            }
            u32x4 d = { rp[0], rp[1], rp[2], rp[3] };
            *(u32x4*)(at + lane * 64 + 8 * (cb ^ (lane & 7))) = d;
        }
    }
    __syncthreads();   // merge writes visible to both waves

    s16x8 wf[2][2];
    #pragma unroll
    for (int t2 = 0; t2 < 2; ++t2)
        #pragma unroll
        for (int ks = 0; ks < 2; ++ks) {
            const float* wp = Wo + (o0 + t2 * 16 + lr) * 64 + ks * 32 + g * 8;
            f32x4 w0 = *(const f32x4*)wp;
            f32x4 w1 = *(const f32x4*)(wp + 4);
            u32x4 d = { pkbf(w0[0], w0[1]), pkbf(w0[2], w0[3]),
                        pkbf(w1[0], w1[1]), pkbf(w1[2], w1[3]) };
            wf[t2][ks] = __builtin_bit_cast(s16x8, d);
        }

    s16x8 af[4][2];
    #pragma unroll
    for (int pt = 0; pt < 4; ++pt)
        #pragma unroll
        for (int ks = 0; ks < 2; ++ks) {
            const int pix = pt * 16 + lr;
            af[pt][ks] = *(const s16x8*)(at + pix * 64 + 8 * ((ks * 4 + g) ^ (pix & 7)));
        }

    f32x4 acc[2][4];
    #pragma unroll
    for (int mt = 0; mt < 2; ++mt) {
        f32x4 bi = *(const f32x4*)(bo + o0 + mt * 16 + g * 4);
        #pragma unroll
        for (int nt = 0; nt < 4; ++nt) acc[mt][nt] = bi;
    }
    #pragma unroll
    for (int ks = 0; ks < 2; ++ks)
        #pragma unroll
        for (int mt = 0; mt < 2; ++mt)
            #pragma unroll
            for (int nt = 0; nt < 4; ++nt)
                acc[mt][nt] = __builtin_amdgcn_mfma_f32_16x16x32_bf16(
                    wf[mt][ks], af[nt][ks], acc[mt][nt], 0, 0, 0);

    #pragma unroll
    for (int mt = 0; mt < 2; ++mt)
        #pragma unroll
        for (int nt = 0; nt < 4; ++nt) {
            const int o = o0 + mt * 16 + g * 4;
            const size_t rowb = ((size_t)(b * 64 + o)) * HW_ + hw0 + nt * 16 + lr;
            #pragma unroll
            for (int r = 0; r < 4; ++r) {
                const size_t a2 = rowb + (size_t)r * HW_;
                out[a2] = acc[mt][nt][r] + x[a2];
            }
        }
}

// ---------------------------------------------------------------------------
extern "C" void kernel_launch(void* const* d_in, const int* in_sizes, int n_in,
                              void* d_out, int out_size, void* d_ws, size_t ws_size,
                              hipStream_t stream) {
    const float* x  = (const float*)d_in[0];
    const float* Wq = (const float*)d_in[1];
    const float* Wk = (const float*)d_in[2];
    const float* Wv = (const float*)d_in[3];
    const float* Wo = (const float*)d_in[4];
    const float* bq = (const float*)d_in[5];
    const float* bk = (const float*)d_in[6];
    const float* bv = (const float*)d_in[7];
    const float* bo = (const float*)d_in[8];
    float* out = (float*)d_out;

    uint16_t* Q  = (uint16_t*)d_ws;
    uint16_t* K  = Q + NPART;
    uint16_t* V  = K + NPART;
    uint16_t* Op = V + NPART;                       // NSPLIT partials
    float*    Lp = (float*)(Op + (size_t)NSPLIT * NPART);

    qkv_fused<<<1152, 192, 0, stream>>>(x, Wq, Wk, Wv, bq, bk, bv, Q, K, V);
    attn<<<576, 256, 0, stream>>>(Q, K, V, Op, Lp);
    out_proj<<<576, 128, 0, stream>>>(Op, Lp, x, Wo, bo, out);
}

// Round 19
// 66.102 us; speedup vs baseline: 1.0397x; 1.0397x over previous
//
#include <hip/hip_runtime.h>
#include <stdint.h>

#define HW_  9216
#define S_   2304
#define NBH  16
#define NSPLIT 4
#define JPS  9          // KV tiles per split (36/4)
#define NPART ((size_t)NBH * S_ * 64)
// 0.5 (softmax scale = 1/sqrt(head_size=4)) * log2(e), folded into Wq/bq
#define SCALE_LOG2E 0.72134752044448169136f

using f32x4 = __attribute__((ext_vector_type(4))) float;
using u32x4 = __attribute__((ext_vector_type(4))) uint32_t;
using u32x2 = __attribute__((ext_vector_type(2))) uint32_t;
using s16x8 = __attribute__((ext_vector_type(8))) short;   // 8 bf16 in 4 VGPRs

typedef const __attribute__((address_space(1))) void gbl_void;
typedef __attribute__((address_space(3))) void lds_void;

__device__ __forceinline__ uint32_t pkbf(float lo, float hi) {
    uint32_t r;
    asm("v_cvt_pk_bf16_f32 %0, %1, %2" : "=v"(r) : "v"(lo), "v"(hi));
    return r;
}
__device__ __forceinline__ float bf2f(uint16_t h) {
    return __builtin_bit_cast(float, (uint32_t)h << 16);
}

// ---------------------------------------------------------------------------
// Kernel 1: FUSED qkv projection, MFMA. grid=576, block=192 (3 waves).
// (byte-exact R10/R14/R17-verified kernel)
// ---------------------------------------------------------------------------
__global__ __launch_bounds__(192) void qkv_fused(
    const float* __restrict__ x,
    const float* __restrict__ Wq, const float* __restrict__ Wk, const float* __restrict__ Wv,
    const float* __restrict__ bq, const float* __restrict__ bk, const float* __restrict__ bv,
    uint16_t* __restrict__ Qo, uint16_t* __restrict__ Ko, uint16_t* __restrict__ Vo)
{
    const int pix0 = blockIdx.x * 64;
    const int b   = pix0 / HW_;
    const int hw0 = pix0 % HW_;
    const int h   = hw0 / S_;          // uniform (S_ % 64 == 0)
    const int s0  = hw0 % S_;
    const int bh  = b * 4 + h;

    const int tid  = threadIdx.x;
    const int wave = tid >> 6;          // 0..2 == mode
    const int lane = tid & 63;
    const int g = lane >> 4, lr = lane & 15;

    __shared__ alignas(16) uint16_t xt[64 * 64];   // [pix][c] bf16, swizzled

    // ---- cooperative x-tile stage: wave0 cb 0-2, wave1 cb 3-5, wave2 cb 6-7 ----
    {
        const float* xb = x + (size_t)b * 64 * HW_ + hw0 + lane;
        const int cb_begin = wave * 3;
        const int cb_end   = (wave == 2) ? 8 : wave * 3 + 3;
        for (int cb = cb_begin; cb < cb_end; ++cb) {
            uint32_t rp[4];
            #pragma unroll
            for (int e = 0; e < 4; ++e)
                rp[e] = pkbf(xb[(size_t)(cb * 8 + 2 * e) * HW_],
                             xb[(size_t)(cb * 8 + 2 * e + 1) * HW_]);
            u32x4 d = { rp[0], rp[1], rp[2], rp[3] };
            *(u32x4*)(xt + lane * 64 + 8 * (cb ^ (lane & 7))) = d;
        }
    }
    __syncthreads();   // all writes visible before any fragment read

    const float* W    = (wave == 0) ? Wq : (wave == 1) ? Wk : Wv;
    const float* bias = (wave == 0) ? bq : (wave == 1) ? bk : bv;
    const float ws = (wave == 0) ? SCALE_LOG2E : 1.0f;

    // ---- W fragments (scale folded for Q) ----
    s16x8 wf[4][2];
    #pragma unroll
    for (int t4 = 0; t4 < 4; ++t4)
        #pragma unroll
        for (int ks = 0; ks < 2; ++ks) {
            const float* wp = W + (t4 * 16 + lr) * 64 + ks * 32 + g * 8;
            f32x4 w0 = *(const f32x4*)wp;
            f32x4 w1 = *(const f32x4*)(wp + 4);
            u32x4 d = { pkbf(w0[0] * ws, w0[1] * ws), pkbf(w0[2] * ws, w0[3] * ws),
                        pkbf(w1[0] * ws, w1[1] * ws), pkbf(w1[2] * ws, w1[3] * ws) };
            wf[t4][ks] = __builtin_bit_cast(s16x8, d);
        }

    // ---- x fragments from LDS ----
    s16x8 xf[4][2];
    #pragma unroll
    for (int pt = 0; pt < 4; ++pt)
        #pragma unroll
        for (int ks = 0; ks < 2; ++ks) {
            const int pix = pt * 16 + lr;
            xf[pt][ks] = *(const s16x8*)(xt + pix * 64 + 8 * ((ks * 4 + g) ^ (pix & 7)));
        }

    if (wave != 2) {
        f32x4 acc[4][4];
        #pragma unroll
        for (int mt = 0; mt < 4; ++mt) {
            f32x4 bi = *(const f32x4*)(bias + mt * 16 + g * 4);
            bi *= ws;
            #pragma unroll
            for (int nt = 0; nt < 4; ++nt) acc[mt][nt] = bi;
        }
        #pragma unroll
        for (int ks = 0; ks < 2; ++ks)
            #pragma unroll
            for (int mt = 0; mt < 4; ++mt)
                #pragma unroll
                for (int nt = 0; nt < 4; ++nt)
                    acc[mt][nt] = __builtin_amdgcn_mfma_f32_16x16x32_bf16(
                        wf[mt][ks], xf[nt][ks], acc[mt][nt], 0, 0, 0);
        uint16_t* dst = ((wave == 0) ? Qo : Ko) + ((size_t)bh * S_ + s0) * 64;
        #pragma unroll
        for (int mt = 0; mt < 4; ++mt)
            #pragma unroll
            for (int nt = 0; nt < 4; ++nt) {
                uint32_t d0 = pkbf(acc[mt][nt][0], acc[mt][nt][1]);
                uint32_t d1 = pkbf(acc[mt][nt][2], acc[mt][nt][3]);
                const int o = mt * 16 + g * 4;
                *(uint32_t*)(dst + (nt * 16 + lr) * 64 + o)     = d0;
                *(uint32_t*)(dst + (nt * 16 + lr) * 64 + o + 2) = d1;
            }
    } else {
        f32x4 acc[4][4];
        #pragma unroll
        for (int nt = 0; nt < 4; ++nt) {
            const float bv = bias[nt * 16 + lr];
            #pragma unroll
            for (int mt = 0; mt < 4; ++mt) acc[mt][nt] = (f32x4){bv, bv, bv, bv};
        }
        #pragma unroll
        for (int ks = 0; ks < 2; ++ks)
            #pragma unroll
            for (int mt = 0; mt < 4; ++mt)
                #pragma unroll
                for (int nt = 0; nt < 4; ++nt)
                    acc[mt][nt] = __builtin_amdgcn_mfma_f32_16x16x32_bf16(
                        xf[mt][ks], wf[nt][ks], acc[mt][nt], 0, 0, 0);
        uint16_t* dst = Vo + (size_t)bh * 64 * S_;
        #pragma unroll
        for (int mt = 0; mt < 4; ++mt)
            #pragma unroll
            for (int nt = 0; nt < 4; ++nt) {
                uint32_t d0 = pkbf(acc[mt][nt][0], acc[mt][nt][1]);
                uint32_t d1 = pkbf(acc[mt][nt][2], acc[mt][nt][3]);
                const int o = nt * 16 + lr;
                const int sb = s0 + mt * 16 + g * 4;
                *(uint32_t*)(dst + (size_t)o * S_ + sb)     = d0;
                *(uint32_t*)(dst + (size_t)o * S_ + sb + 2) = d1;
            }
    }
}

// ---------------------------------------------------------------------------
// Kernel 2: flash attention, no-max softmax, split-KV x4. grid=1152, block=256.
// BYTE-EXACT R7/R10/R14/R17-verified body; ONLY change: __launch_bounds__
// min-waves/EU 3 -> 4. Regs = 60 VGPR + 64 AGPR = 124 <= 128, so the 4-wave
// contract is satisfiable without spills; expectation is 4 blocks/CU resident
// (was ~2). Serialized staging: stage -> vmcnt(0) -> barrier -> compute ->
// barrier. Stores UNNORMALIZED bf16 partial-O + f32 partial-l.
// DO NOT restructure staging/P-lifetime (R4/5/8/9/13/15/16 all failed there).
// ---------------------------------------------------------------------------
__global__ __launch_bounds__(256, 4) void attn(
    const uint16_t* __restrict__ Qg, const uint16_t* __restrict__ Kg,
    const uint16_t* __restrict__ Vg, uint16_t* __restrict__ Op,
    float* __restrict__ Lp)
{
    const int blk = blockIdx.x;          // 1152 = 8 xcd * 2 bh * (4 sp * 18 qb)
    const int xcd = blk & 7;
    const int i   = blk >> 3;            // 0..143
    const int bh  = xcd * 2 + (i & 1);
    const int i2  = i >> 1;              // 0..71
    const int sp  = i2 & 3;
    const int qb  = i2 >> 2;             // 0..17
    const int j0  = sp * JPS;
    const int b   = bh >> 2;
    const int h   = bh & 3;

    const int tid  = threadIdx.x;
    const int wave = tid >> 6;
    const int lane = tid & 63;
    const int g    = lane >> 4;
    const int lr   = lane & 15;
    const int q0   = qb * 128 + wave * 32;

    __shared__ alignas(16) uint16_t Kl[4096];      // [key][c] swizzled
    __shared__ alignas(16) uint16_t Vl[4096];      // [c][s]   swizzled
    __shared__ alignas(16) uint16_t Pw[4][2304];   // per-wave P (stride 72) / out-bounce (stride 36)
    uint16_t* P = Pw[wave];

    const uint16_t* Qb = Qg + (size_t)bh * S_ * 64;
    const uint16_t* Kb = Kg + (size_t)bh * S_ * 64;
    const uint16_t* Vb = Vg + (size_t)bh * 64 * S_;

    s16x8 qf[2][2];
    #pragma unroll
    for (int qt = 0; qt < 2; ++qt)
        #pragma unroll
        for (int ks = 0; ks < 2; ++ks)
            qf[qt][ks] = *(const s16x8*)(Qb + (size_t)(q0 + qt * 16 + lr) * 64 + ks * 32 + g * 8);

    f32x4 oacc[2][4];
    float l_r[2][4];
    #pragma unroll
    for (int qt = 0; qt < 2; ++qt) {
        #pragma unroll
        for (int ct = 0; ct < 4; ++ct) oacc[qt][ct] = (f32x4){0.f, 0.f, 0.f, 0.f};
        #pragma unroll
        for (int r = 0; r < 4; ++r) l_r[qt][r] = 0.f;
    }

    for (int jj = 0; jj < JPS; ++jj) {
        const int j = j0 + jj;
        // ---- stage K/V tile (serialized; each wave stages its quarter) ----
        #pragma unroll
        for (int call = 0; call < 2; ++call) {
            const int chunk = wave * 128 + call * 64 + lane;   // 16B units
            const int row   = chunk >> 3;
            const int cb    = (chunk & 7) ^ (row & 7);         // pre-swizzled source
            __builtin_amdgcn_global_load_lds(
                (gbl_void*)(Kb + ((size_t)(j * 64 + row) * 64 + cb * 8)),
                (lds_void*)(Kl + (wave * 128 + call * 64) * 8), 16, 0, 0);
            __builtin_amdgcn_global_load_lds(
                (gbl_void*)(Vb + ((size_t)row * S_ + j * 64 + cb * 8)),
                (lds_void*)(Vl + (wave * 128 + call * 64) * 8), 16, 0, 0);
        }
        asm volatile("s_waitcnt vmcnt(0)" ::: "memory");
        __syncthreads();

        // ---- S = Q K^T (logits pre-scaled into exp2 domain) ----
        f32x4 sacc[2][4];
        #pragma unroll
        for (int qt = 0; qt < 2; ++qt)
            #pragma unroll
            for (int kt = 0; kt < 4; ++kt) sacc[qt][kt] = (f32x4){0.f, 0.f, 0.f, 0.f};
        #pragma unroll
        for (int ks = 0; ks < 2; ++ks)
            #pragma unroll
            for (int kt = 0; kt < 4; ++kt) {
                const int key = kt * 16 + lr;
                s16x8 kf = *(const s16x8*)(&Kl[key * 64 + 8 * ((ks * 4 + g) ^ (key & 7))]);
                sacc[0][kt] = __builtin_amdgcn_mfma_f32_16x16x32_bf16(qf[0][ks], kf, sacc[0][kt], 0, 0, 0);
                sacc[1][kt] = __builtin_amdgcn_mfma_f32_16x16x32_bf16(qf[1][ks], kf, sacc[1][kt], 0, 0, 0);
            }

        // ---- P = exp2(S), lane-partial l, P -> wave-private LDS ----
        #pragma unroll
        for (int qt = 0; qt < 2; ++qt)
            #pragma unroll
            for (int kt = 0; kt < 4; ++kt)
                #pragma unroll
                for (int r = 0; r < 4; ++r) {
                    const float pv = __builtin_amdgcn_exp2f(sacc[qt][kt][r]);
                    l_r[qt][r] += pv;
                    P[(qt * 16 + 4 * g + r) * 72 + kt * 16 + lr] = (uint16_t)pkbf(pv, pv);
                }

        // ---- PV ----
        #pragma unroll
        for (int ks = 0; ks < 2; ++ks) {
            s16x8 pf0 = *(const s16x8*)(P + (0 * 16 + lr) * 72 + ks * 32 + g * 8);
            s16x8 pf1 = *(const s16x8*)(P + (1 * 16 + lr) * 72 + ks * 32 + g * 8);
            #pragma unroll
            for (int ct = 0; ct < 4; ++ct) {
                const int c = ct * 16 + lr;
                s16x8 vf = *(const s16x8*)(&Vl[c * 64 + 8 * ((ks * 4 + g) ^ (c & 7))]);
                oacc[0][ct] = __builtin_amdgcn_mfma_f32_16x16x32_bf16(pf0, vf, oacc[0][ct], 0, 0, 0);
                oacc[1][ct] = __builtin_amdgcn_mfma_f32_16x16x32_bf16(pf1, vf, oacc[1][ct], 0, 0, 0);
            }
        }

        __syncthreads();   // all waves done reading Kl/Vl before next stage
    }

    // ---- reduce l over the 16-lane group ----
    #pragma unroll
    for (int mask = 1; mask < 16; mask <<= 1) {
        #pragma unroll
        for (int qt = 0; qt < 2; ++qt)
            #pragma unroll
            for (int r = 0; r < 4; ++r)
                l_r[qt][r] += __shfl_xor(l_r[qt][r], mask, 64);
    }

    // ---- bounce UNNORMALIZED O as [c][t] (stride 36 u16) into own P region ----
    #pragma unroll
    for (int qt = 0; qt < 2; ++qt)
        #pragma unroll
        for (int ct = 0; ct < 4; ++ct) {
            uint32_t d0 = pkbf(oacc[qt][ct][0], oacc[qt][ct][1]);
            uint32_t d1 = pkbf(oacc[qt][ct][2], oacc[qt][ct][3]);
            const int base = (ct * 16 + lr) * 36 + qt * 16 + 4 * g;
            *(uint32_t*)(P + base)     = d0;
            *(uint32_t*)(P + base + 2) = d1;
        }
    __syncthreads();   // order cross-lane bounce write -> read

    // ---- scrambled-layout store: lane owns channel c, 32 consecutive t ----
    const int c = lane;
    u32x2 wv[8];
    #pragma unroll
    for (int e = 0; e < 8; ++e)
        wv[e] = *(const u32x2*)(P + c * 36 + e * 4);
    uint16_t* dst = Op + (size_t)sp * NPART
                  + ((size_t)(b * 64 + h * 16 + (c >> 2)) * HW_ + (c & 3) * S_ + q0);
    #pragma unroll
    for (int s4 = 0; s4 < 4; ++s4) {
        u32x4 d = { wv[2 * s4][0], wv[2 * s4][1], wv[2 * s4 + 1][0], wv[2 * s4 + 1][1] };
        *(u32x4*)(dst + s4 * 8) = d;
    }

    if (lr == 0) {
        #pragma unroll
        for (int qt = 0; qt < 2; ++qt)
            #pragma unroll
            for (int r = 0; r < 4; ++r)
                Lp[((size_t)sp * NBH + bh) * S_ + q0 + qt * 16 + 4 * g + r] = l_r[qt][r];
    }
}

// ---------------------------------------------------------------------------
// Kernel 3: merge splits + output projection + residual, MFMA.
// grid=576, block=128 (2 waves). (byte-exact R14/R17-verified cooperative kernel)
// ---------------------------------------------------------------------------
__global__ __launch_bounds__(128) void out_proj(
    const uint16_t* __restrict__ Op, const float* __restrict__ Lp,
    const float* __restrict__ x,
    const float* __restrict__ Wo, const float* __restrict__ bo,
    float* __restrict__ out)
{
    const int pix0 = blockIdx.x * 64;
    const int b   = pix0 / HW_;
    const int hw0 = pix0 % HW_;
    const int tid  = threadIdx.x;
    const int wave = tid >> 6;           // 0..1
    const int lane = tid & 63;
    const int g = lane >> 4, lr = lane & 15;
    const int o0 = wave * 32;
    const int t = (hw0 % S_) + lane;     // token of own pixel

    __shared__ alignas(16) uint16_t at[64 * 64];   // [pix][c'] bf16, swizzled

    float inv[4];
    #pragma unroll
    for (int hh = 0; hh < 4; ++hh) {
        float sl = 0.f;
        #pragma unroll
        for (int sp2 = 0; sp2 < NSPLIT; ++sp2)
            sl += Lp[((size_t)sp2 * NBH + b * 4 + hh) * S_ + t];
        inv[hh] = 1.0f / sl;
    }

    // ---- cooperative merge: wave w handles cb in [4w, 4w+4) (8 ch each) ----
    {
        const size_t base = (size_t)b * 64 * HW_ + hw0 + lane;
        #pragma unroll
        for (int cbi = 0; cbi < 4; ++cbi) {
            const int cb = wave * 4 + cbi;
            uint32_t rp[4];
            #pragma unroll
            for (int e = 0; e < 4; ++e) {
                const int cc = cb * 4 + e;          // channel pair (2cc, 2cc+1)
                float a0 = 0.f, a1 = 0.f;
                #pragma unroll
                for (int sp2 = 0; sp2 < NSPLIT; ++sp2) {
                    const size_t o2 = (size_t)sp2 * NPART + base;
                    a0 += bf2f(Op[o2 + (size_t)(2 * cc) * HW_]);
                    a1 += bf2f(Op[o2 + (size_t)(2 * cc + 1) * HW_]);
                }
                rp[e] = pkbf(a0 * inv[(2 * cc) >> 4], a1 * inv[(2 * cc + 1) >> 4]);
            }
            u32x4 d = { rp[0], rp[1], rp[2], rp[3] };
            *(u32x4*)(at + lane * 64 + 8 * (cb ^ (lane & 7))) = d;
        }
    }
    __syncthreads();   // merge writes visible to both waves

    s16x8 wf[2][2];
    #pragma unroll
    for (int t2 = 0; t2 < 2; ++t2)
        #pragma unroll
        for (int ks = 0; ks < 2; ++ks) {
            const float* wp = Wo + (o0 + t2 * 16 + lr) * 64 + ks * 32 + g * 8;
            f32x4 w0 = *(const f32x4*)wp;
            f32x4 w1 = *(const f32x4*)(wp + 4);
            u32x4 d = { pkbf(w0[0], w0[1]), pkbf(w0[2], w0[3]),
                        pkbf(w1[0], w1[1]), pkbf(w1[2], w1[3]) };
            wf[t2][ks] = __builtin_bit_cast(s16x8, d);
        }

    s16x8 af[4][2];
    #pragma unroll
    for (int pt = 0; pt < 4; ++pt)
        #pragma unroll
        for (int ks = 0; ks < 2; ++ks) {
            const int pix = pt * 16 + lr;
            af[pt][ks] = *(const s16x8*)(at + pix * 64 + 8 * ((ks * 4 + g) ^ (pix & 7)));
        }

    f32x4 acc[2][4];
    #pragma unroll
    for (int mt = 0; mt < 2; ++mt) {
        f32x4 bi = *(const f32x4*)(bo + o0 + mt * 16 + g * 4);
        #pragma unroll
        for (int nt = 0; nt < 4; ++nt) acc[mt][nt] = bi;
    }
    #pragma unroll
    for (int ks = 0; ks < 2; ++ks)
        #pragma unroll
        for (int mt = 0; mt < 2; ++mt)
            #pragma unroll
            for (int nt = 0; nt < 4; ++nt)
                acc[mt][nt] = __builtin_amdgcn_mfma_f32_16x16x32_bf16(
                    wf[mt][ks], af[nt][ks], acc[mt][nt], 0, 0, 0);

    #pragma unroll
    for (int mt = 0; mt < 2; ++mt)
        #pragma unroll
        for (int nt = 0; nt < 4; ++nt) {
            const int o = o0 + mt * 16 + g * 4;
            const size_t rowb = ((size_t)(b * 64 + o)) * HW_ + hw0 + nt * 16 + lr;
            #pragma unroll
            for (int r = 0; r < 4; ++r) {
                const size_t a2 = rowb + (size_t)r * HW_;
                out[a2] = acc[mt][nt][r] + x[a2];
            }
        }
}

// ---------------------------------------------------------------------------
extern "C" void kernel_launch(void* const* d_in, const int* in_sizes, int n_in,
                              void* d_out, int out_size, void* d_ws, size_t ws_size,
                              hipStream_t stream) {
    const float* x  = (const float*)d_in[0];
    const float* Wq = (const float*)d_in[1];
    const float* Wk = (const float*)d_in[2];
    const float* Wv = (const float*)d_in[3];
    const float* Wo = (const float*)d_in[4];
    const float* bq = (const float*)d_in[5];
    const float* bk = (const float*)d_in[6];
    const float* bv = (const float*)d_in[7];
    const float* bo = (const float*)d_in[8];
    float* out = (float*)d_out;

    uint16_t* Q  = (uint16_t*)d_ws;
    uint16_t* K  = Q + NPART;
    uint16_t* V  = K + NPART;
    uint16_t* Op = V + NPART;                       // NSPLIT partials
    float*    Lp = (float*)(Op + (size_t)NSPLIT * NPART);

    qkv_fused<<<576, 192, 0, stream>>>(x, Wq, Wk, Wv, bq, bk, bv, Q, K, V);
    attn<<<1152, 256, 0, stream>>>(Q, K, V, Op, Lp);
    out_proj<<<576, 128, 0, stream>>>(Op, Lp, x, Wo, bo, out);
}

// Round 20
// 65.989 us; speedup vs baseline: 1.0415x; 1.0017x over previous
//
#include <hip/hip_runtime.h>
#include <stdint.h>

#define HW_  9216
#define S_   2304
#define NBH  16
#define NSPLIT 4
#define JPS  9          // KV tiles per split (36/4)
#define NPART ((size_t)NBH * S_ * 64)
// 0.5 (softmax scale = 1/sqrt(head_size=4)) * log2(e), folded into Wq/bq
#define SCALE_LOG2E 0.72134752044448169136f

using f32x4 = __attribute__((ext_vector_type(4))) float;
using u32x4 = __attribute__((ext_vector_type(4))) uint32_t;
using u32x2 = __attribute__((ext_vector_type(2))) uint32_t;
using s16x8 = __attribute__((ext_vector_type(8))) short;   // 8 bf16 in 4 VGPRs

typedef const __attribute__((address_space(1))) void gbl_void;
typedef __attribute__((address_space(3))) void lds_void;

__device__ __forceinline__ uint32_t pkbf(float lo, float hi) {
    uint32_t r;
    asm("v_cvt_pk_bf16_f32 %0, %1, %2" : "=v"(r) : "v"(lo), "v"(hi));
    return r;
}
__device__ __forceinline__ float bf2f(uint16_t h) {
    return __builtin_bit_cast(float, (uint32_t)h << 16);
}

// ---------------------------------------------------------------------------
// Kernel 1: FUSED qkv projection, MFMA. grid=576, block=192 (3 waves).
// (byte-exact R10/R14/R17/R19-verified kernel)
// ---------------------------------------------------------------------------
__global__ __launch_bounds__(192) void qkv_fused(
    const float* __restrict__ x,
    const float* __restrict__ Wq, const float* __restrict__ Wk, const float* __restrict__ Wv,
    const float* __restrict__ bq, const float* __restrict__ bk, const float* __restrict__ bv,
    uint16_t* __restrict__ Qo, uint16_t* __restrict__ Ko, uint16_t* __restrict__ Vo)
{
    const int pix0 = blockIdx.x * 64;
    const int b   = pix0 / HW_;
    const int hw0 = pix0 % HW_;
    const int h   = hw0 / S_;          // uniform (S_ % 64 == 0)
    const int s0  = hw0 % S_;
    const int bh  = b * 4 + h;

    const int tid  = threadIdx.x;
    const int wave = tid >> 6;          // 0..2 == mode
    const int lane = tid & 63;
    const int g = lane >> 4, lr = lane & 15;

    __shared__ alignas(16) uint16_t xt[64 * 64];   // [pix][c] bf16, swizzled

    // ---- cooperative x-tile stage: wave0 cb 0-2, wave1 cb 3-5, wave2 cb 6-7 ----
    {
        const float* xb = x + (size_t)b * 64 * HW_ + hw0 + lane;
        const int cb_begin = wave * 3;
        const int cb_end   = (wave == 2) ? 8 : wave * 3 + 3;
        for (int cb = cb_begin; cb < cb_end; ++cb) {
            uint32_t rp[4];
            #pragma unroll
            for (int e = 0; e < 4; ++e)
                rp[e] = pkbf(xb[(size_t)(cb * 8 + 2 * e) * HW_],
                             xb[(size_t)(cb * 8 + 2 * e + 1) * HW_]);
            u32x4 d = { rp[0], rp[1], rp[2], rp[3] };
            *(u32x4*)(xt + lane * 64 + 8 * (cb ^ (lane & 7))) = d;
        }
    }
    __syncthreads();   // all writes visible before any fragment read

    const float* W    = (wave == 0) ? Wq : (wave == 1) ? Wk : Wv;
    const float* bias = (wave == 0) ? bq : (wave == 1) ? bk : bv;
    const float ws = (wave == 0) ? SCALE_LOG2E : 1.0f;

    // ---- W fragments (scale folded for Q) ----
    s16x8 wf[4][2];
    #pragma unroll
    for (int t4 = 0; t4 < 4; ++t4)
        #pragma unroll
        for (int ks = 0; ks < 2; ++ks) {
            const float* wp = W + (t4 * 16 + lr) * 64 + ks * 32 + g * 8;
            f32x4 w0 = *(const f32x4*)wp;
            f32x4 w1 = *(const f32x4*)(wp + 4);
            u32x4 d = { pkbf(w0[0] * ws, w0[1] * ws), pkbf(w0[2] * ws, w0[3] * ws),
                        pkbf(w1[0] * ws, w1[1] * ws), pkbf(w1[2] * ws, w1[3] * ws) };
            wf[t4][ks] = __builtin_bit_cast(s16x8, d);
        }

    // ---- x fragments from LDS ----
    s16x8 xf[4][2];
    #pragma unroll
    for (int pt = 0; pt < 4; ++pt)
        #pragma unroll
        for (int ks = 0; ks < 2; ++ks) {
            const int pix = pt * 16 + lr;
            xf[pt][ks] = *(const s16x8*)(xt + pix * 64 + 8 * ((ks * 4 + g) ^ (pix & 7)));
        }

    if (wave != 2) {
        f32x4 acc[4][4];
        #pragma unroll
        for (int mt = 0; mt < 4; ++mt) {
            f32x4 bi = *(const f32x4*)(bias + mt * 16 + g * 4);
            bi *= ws;
            #pragma unroll
            for (int nt = 0; nt < 4; ++nt) acc[mt][nt] = bi;
        }
        #pragma unroll
        for (int ks = 0; ks < 2; ++ks)
            #pragma unroll
            for (int mt = 0; mt < 4; ++mt)
                #pragma unroll
                for (int nt = 0; nt < 4; ++nt)
                    acc[mt][nt] = __builtin_amdgcn_mfma_f32_16x16x32_bf16(
                        wf[mt][ks], xf[nt][ks], acc[mt][nt], 0, 0, 0);
        uint16_t* dst = ((wave == 0) ? Qo : Ko) + ((size_t)bh * S_ + s0) * 64;
        #pragma unroll
        for (int mt = 0; mt < 4; ++mt)
            #pragma unroll
            for (int nt = 0; nt < 4; ++nt) {
                uint32_t d0 = pkbf(acc[mt][nt][0], acc[mt][nt][1]);
                uint32_t d1 = pkbf(acc[mt][nt][2], acc[mt][nt][3]);
                const int o = mt * 16 + g * 4;
                *(uint32_t*)(dst + (nt * 16 + lr) * 64 + o)     = d0;
                *(uint32_t*)(dst + (nt * 16 + lr) * 64 + o + 2) = d1;
            }
    } else {
        f32x4 acc[4][4];
        #pragma unroll
        for (int nt = 0; nt < 4; ++nt) {
            const float bv = bias[nt * 16 + lr];
            #pragma unroll
            for (int mt = 0; mt < 4; ++mt) acc[mt][nt] = (f32x4){bv, bv, bv, bv};
        }
        #pragma unroll
        for (int ks = 0; ks < 2; ++ks)
            #pragma unroll
            for (int mt = 0; mt < 4; ++mt)
                #pragma unroll
                for (int nt = 0; nt < 4; ++nt)
                    acc[mt][nt] = __builtin_amdgcn_mfma_f32_16x16x32_bf16(
                        xf[mt][ks], wf[nt][ks], acc[mt][nt], 0, 0, 0);
        uint16_t* dst = Vo + (size_t)bh * 64 * S_;
        #pragma unroll
        for (int mt = 0; mt < 4; ++mt)
            #pragma unroll
            for (int nt = 0; nt < 4; ++nt) {
                uint32_t d0 = pkbf(acc[mt][nt][0], acc[mt][nt][1]);
                uint32_t d1 = pkbf(acc[mt][nt][2], acc[mt][nt][3]);
                const int o = nt * 16 + lr;
                const int sb = s0 + mt * 16 + g * 4;
                *(uint32_t*)(dst + (size_t)o * S_ + sb)     = d0;
                *(uint32_t*)(dst + (size_t)o * S_ + sb + 2) = d1;
            }
    }
}

// ---------------------------------------------------------------------------
// Kernel 2: flash attention, no-max softmax, split-KV x4. grid=1152, block=512
// (8 waves x 16 queries — thinner waves, SAME verified skeleton:
//   stage -> vmcnt(0) -> barrier -> compute -> barrier).
// Per-wave state halves (qf 1 qt; sacc/oacc 16 regs each) -> ~2x waves/SIMD
// schedulable during drains. Per-wave staging: exactly 1 K + 1 V
// global_load_lds (8 waves x 64 lanes = 512 chunks, same coverage).
// P is per-wave-private, written then read once per interval (anchor
// lifecycle). Per-query math identical to the anchor -> bit-identical output.
// Stores UNNORMALIZED bf16 partial-O + f32 partial-l; out_proj merges.
// DO NOT restructure staging/P-lifetime (R4/5/8/9/13/15/16 all failed there).
// ---------------------------------------------------------------------------
__global__ __launch_bounds__(512, 4) void attn(
    const uint16_t* __restrict__ Qg, const uint16_t* __restrict__ Kg,
    const uint16_t* __restrict__ Vg, uint16_t* __restrict__ Op,
    float* __restrict__ Lp)
{
    const int blk = blockIdx.x;          // 1152 = 8 xcd * 2 bh * (4 sp * 18 qb)
    const int xcd = blk & 7;
    const int i   = blk >> 3;            // 0..143
    const int bh  = xcd * 2 + (i & 1);
    const int i2  = i >> 1;              // 0..71
    const int sp  = i2 & 3;
    const int qb  = i2 >> 2;             // 0..17
    const int j0  = sp * JPS;
    const int b   = bh >> 2;
    const int h   = bh & 3;

    const int tid  = threadIdx.x;
    const int wave = tid >> 6;           // 0..7
    const int lane = tid & 63;
    const int g    = lane >> 4;
    const int lr   = lane & 15;
    const int q0   = qb * 128 + wave * 16;

    __shared__ alignas(16) uint16_t Kl[4096];      // [key][c] swizzled
    __shared__ alignas(16) uint16_t Vl[4096];      // [c][s]   swizzled
    __shared__ alignas(16) uint16_t Pw[8][1280];   // per-wave P (16 rows, stride 72) / bounce (stride 20)
    uint16_t* P = Pw[wave];

    const uint16_t* Qb = Qg + (size_t)bh * S_ * 64;
    const uint16_t* Kb = Kg + (size_t)bh * S_ * 64;
    const uint16_t* Vb = Vg + (size_t)bh * 64 * S_;

    s16x8 qf[2];
    #pragma unroll
    for (int ks = 0; ks < 2; ++ks)
        qf[ks] = *(const s16x8*)(Qb + (size_t)(q0 + lr) * 64 + ks * 32 + g * 8);

    f32x4 oacc[4];
    float l_r[4];
    #pragma unroll
    for (int ct = 0; ct < 4; ++ct) oacc[ct] = (f32x4){0.f, 0.f, 0.f, 0.f};
    #pragma unroll
    for (int r = 0; r < 4; ++r) l_r[r] = 0.f;

    for (int jj = 0; jj < JPS; ++jj) {
        const int j = j0 + jj;
        // ---- stage K/V tile: 1 K + 1 V chunk per lane (512 chunks total) ----
        {
            const int chunk = wave * 64 + lane;    // 16B units, 0..511
            const int row   = chunk >> 3;
            const int cb    = (chunk & 7) ^ (row & 7);   // pre-swizzled source
            __builtin_amdgcn_global_load_lds(
                (gbl_void*)(Kb + ((size_t)(j * 64 + row) * 64 + cb * 8)),
                (lds_void*)(Kl + (wave * 64) * 8), 16, 0, 0);
            __builtin_amdgcn_global_load_lds(
                (gbl_void*)(Vb + ((size_t)row * S_ + j * 64 + cb * 8)),
                (lds_void*)(Vl + (wave * 64) * 8), 16, 0, 0);
        }
        asm volatile("s_waitcnt vmcnt(0)" ::: "memory");
        __syncthreads();

        // ---- S = Q K^T (logits pre-scaled into exp2 domain) ----
        f32x4 sacc[4];
        #pragma unroll
        for (int kt = 0; kt < 4; ++kt) sacc[kt] = (f32x4){0.f, 0.f, 0.f, 0.f};
        #pragma unroll
        for (int ks = 0; ks < 2; ++ks)
            #pragma unroll
            for (int kt = 0; kt < 4; ++kt) {
                const int key = kt * 16 + lr;
                s16x8 kf = *(const s16x8*)(&Kl[key * 64 + 8 * ((ks * 4 + g) ^ (key & 7))]);
                sacc[kt] = __builtin_amdgcn_mfma_f32_16x16x32_bf16(qf[ks], kf, sacc[kt], 0, 0, 0);
            }

        // ---- P = exp2(S), lane-partial l, P -> wave-private LDS ----
        #pragma unroll
        for (int kt = 0; kt < 4; ++kt)
            #pragma unroll
            for (int r = 0; r < 4; ++r) {
                const float pv = __builtin_amdgcn_exp2f(sacc[kt][r]);
                l_r[r] += pv;
                P[(4 * g + r) * 72 + kt * 16 + lr] = (uint16_t)pkbf(pv, pv);
            }

        // ---- PV ----
        #pragma unroll
        for (int ks = 0; ks < 2; ++ks) {
            s16x8 pf = *(const s16x8*)(P + lr * 72 + ks * 32 + g * 8);
            #pragma unroll
            for (int ct = 0; ct < 4; ++ct) {
                const int c = ct * 16 + lr;
                s16x8 vf = *(const s16x8*)(&Vl[c * 64 + 8 * ((ks * 4 + g) ^ (c & 7))]);
                oacc[ct] = __builtin_amdgcn_mfma_f32_16x16x32_bf16(pf, vf, oacc[ct], 0, 0, 0);
            }
        }

        __syncthreads();   // all waves done reading Kl/Vl before next stage
    }

    // ---- reduce l over the 16-lane group ----
    #pragma unroll
    for (int mask = 1; mask < 16; mask <<= 1) {
        #pragma unroll
        for (int r = 0; r < 4; ++r)
            l_r[r] += __shfl_xor(l_r[r], mask, 64);
    }

    // ---- bounce UNNORMALIZED O as [c][t16] (stride 20 u16) into own P region ----
    #pragma unroll
    for (int ct = 0; ct < 4; ++ct) {
        uint32_t d0 = pkbf(oacc[ct][0], oacc[ct][1]);
        uint32_t d1 = pkbf(oacc[ct][2], oacc[ct][3]);
        const int base = (ct * 16 + lr) * 20 + 4 * g;
        *(uint32_t*)(P + base)     = d0;
        *(uint32_t*)(P + base + 2) = d1;
    }
    __syncthreads();   // order cross-lane bounce write -> read

    // ---- scrambled-layout store: lane owns channel c, 16 consecutive t ----
    const int c = lane;
    u32x2 wv[4];
    #pragma unroll
    for (int e = 0; e < 4; ++e)
        wv[e] = *(const u32x2*)(P + c * 20 + e * 4);
    uint16_t* dst = Op + (size_t)sp * NPART
                  + ((size_t)(b * 64 + h * 16 + (c >> 2)) * HW_ + (c & 3) * S_ + q0);
    {
        u32x4 d0 = { wv[0][0], wv[0][1], wv[1][0], wv[1][1] };
        u32x4 d1 = { wv[2][0], wv[2][1], wv[3][0], wv[3][1] };
        *(u32x4*)(dst)     = d0;
        *(u32x4*)(dst + 8) = d1;
    }

    if (lr == 0) {
        #pragma unroll
        for (int r = 0; r < 4; ++r)
            Lp[((size_t)sp * NBH + bh) * S_ + q0 + 4 * g + r] = l_r[r];
    }
}

// ---------------------------------------------------------------------------
// Kernel 3: merge splits + output projection + residual, MFMA.
// grid=576, block=128 (2 waves). (byte-exact R14/R17/R19-verified kernel)
// ---------------------------------------------------------------------------
__global__ __launch_bounds__(128) void out_proj(
    const uint16_t* __restrict__ Op, const float* __restrict__ Lp,
    const float* __restrict__ x,
    const float* __restrict__ Wo, const float* __restrict__ bo,
    float* __restrict__ out)
{
    const int pix0 = blockIdx.x * 64;
    const int b   = pix0 / HW_;
    const int hw0 = pix0 % HW_;
    const int tid  = threadIdx.x;
    const int wave = tid >> 6;           // 0..1
    const int lane = tid & 63;
    const int g = lane >> 4, lr = lane & 15;
    const int o0 = wave * 32;
    const int t = (hw0 % S_) + lane;     // token of own pixel

    __shared__ alignas(16) uint16_t at[64 * 64];   // [pix][c'] bf16, swizzled

    float inv[4];
    #pragma unroll
    for (int hh = 0; hh < 4; ++hh) {
        float sl = 0.f;
        #pragma unroll
        for (int sp2 = 0; sp2 < NSPLIT; ++sp2)
            sl += Lp[((size_t)sp2 * NBH + b * 4 + hh) * S_ + t];
        inv[hh] = 1.0f / sl;
    }

    // ---- cooperative merge: wave w handles cb in [4w, 4w+4) (8 ch each) ----
    {
        const size_t base = (size_t)b * 64 * HW_ + hw0 + lane;
        #pragma unroll
        for (int cbi = 0; cbi < 4; ++cbi) {
            const int cb = wave * 4 + cbi;
            uint32_t rp[4];
            #pragma unroll
            for (int e = 0; e < 4; ++e) {
                const int cc = cb * 4 + e;          // channel pair (2cc, 2cc+1)
                float a0 = 0.f, a1 = 0.f;
                #pragma unroll
                for (int sp2 = 0; sp2 < NSPLIT; ++sp2) {
                    const size_t o2 = (size_t)sp2 * NPART + base;
                    a0 += bf2f(Op[o2 + (size_t)(2 * cc) * HW_]);
                    a1 += bf2f(Op[o2 + (size_t)(2 * cc + 1) * HW_]);
                }
                rp[e] = pkbf(a0 * inv[(2 * cc) >> 4], a1 * inv[(2 * cc + 1) >> 4]);
            }
            u32x4 d = { rp[0], rp[1], rp[2], rp[3] };
            *(u32x4*)(at + lane * 64 + 8 * (cb ^ (lane & 7))) = d;
        }
    }
    __syncthreads();   // merge writes visible to both waves

    s16x8 wf[2][2];
    #pragma unroll
    for (int t2 = 0; t2 < 2; ++t2)
        #pragma unroll
        for (int ks = 0; ks < 2; ++ks) {
            const float* wp = Wo + (o0 + t2 * 16 + lr) * 64 + ks * 32 + g * 8;
            f32x4 w0 = *(const f32x4*)wp;
            f32x4 w1 = *(const f32x4*)(wp + 4);
            u32x4 d = { pkbf(w0[0], w0[1]), pkbf(w0[2], w0[3]),
                        pkbf(w1[0], w1[1]), pkbf(w1[2], w1[3]) };
            wf[t2][ks] = __builtin_bit_cast(s16x8, d);
        }

    s16x8 af[4][2];
    #pragma unroll
    for (int pt = 0; pt < 4; ++pt)
        #pragma unroll
        for (int ks = 0; ks < 2; ++ks) {
            const int pix = pt * 16 + lr;
            af[pt][ks] = *(const s16x8*)(at + pix * 64 + 8 * ((ks * 4 + g) ^ (pix & 7)));
        }

    f32x4 acc[2][4];
    #pragma unroll
    for (int mt = 0; mt < 2; ++mt) {
        f32x4 bi = *(const f32x4*)(bo + o0 + mt * 16 + g * 4);
        #pragma unroll
        for (int nt = 0; nt < 4; ++nt) acc[mt][nt] = bi;
    }
    #pragma unroll
    for (int ks = 0; ks < 2; ++ks)
        #pragma unroll
        for (int mt = 0; mt < 2; ++mt)
            #pragma unroll
            for (int nt = 0; nt < 4; ++nt)
                acc[mt][nt] = __builtin_amdgcn_mfma_f32_16x16x32_bf16(
                    wf[mt][ks], af[nt][ks], acc[mt][nt], 0, 0, 0);

    #pragma unroll
    for (int mt = 0; mt < 2; ++mt)
        #pragma unroll
        for (int nt = 0; nt < 4; ++nt) {
            const int o = o0 + mt * 16 + g * 4;
            const size_t rowb = ((size_t)(b * 64 + o)) * HW_ + hw0 + nt * 16 + lr;
            #pragma unroll
            for (int r = 0; r < 4; ++r) {
                const size_t a2 = rowb + (size_t)r * HW_;
                out[a2] = acc[mt][nt][r] + x[a2];
            }
        }
}

// ---------------------------------------------------------------------------
extern "C" void kernel_launch(void* const* d_in, const int* in_sizes, int n_in,
                              void* d_out, int out_size, void* d_ws, size_t ws_size,
                              hipStream_t stream) {
    const float* x  = (const float*)d_in[0];
    const float* Wq = (const float*)d_in[1];
    const float* Wk = (const float*)d_in[2];
    const float* Wv = (const float*)d_in[3];
    const float* Wo = (const float*)d_in[4];
    const float* bq = (const float*)d_in[5];
    const float* bk = (const float*)d_in[6];
    const float* bv = (const float*)d_in[7];
    const float* bo = (const float*)d_in[8];
    float* out = (float*)d_out;

    uint16_t* Q  = (uint16_t*)d_ws;
    uint16_t* K  = Q + NPART;
    uint16_t* V  = K + NPART;
    uint16_t* Op = V + NPART;                       // NSPLIT partials
    float*    Lp = (float*)(Op + (size_t)NSPLIT * NPART);

    qkv_fused<<<576, 192, 0, stream>>>(x, Wq, Wk, Wv, bq, bk, bv, Q, K, V);
    attn<<<1152, 512, 0, stream>>>(Q, K, V, Op, Lp);
    out_proj<<<576, 128, 0, stream>>>(Op, Lp, x, Wo, bo, out);
}